// Round 22
// baseline (662.020 us; speedup 1.0000x reference)
//
#include <hip/hip_runtime.h>
#include <cstdint>
#include <cstddef>

#define NTOK  2048
#define HIDN  2048
#define IM    768
#define NE    32
#define TOPK  8
#define NGRP  8
#define GSZ   4
#define TKG   4

typedef __attribute__((ext_vector_type(8))) short bf16x8_t;
typedef __attribute__((ext_vector_type(4))) float f32x4_t;

__device__ __forceinline__ unsigned short f2bf(float f) {
    union { float f; unsigned u; } v; v.f = f;
    unsigned r = v.u + 0x7FFFu + ((v.u >> 16) & 1u);
    return (unsigned short)(r >> 16);
}
__device__ __forceinline__ float bf2f(unsigned short h) {
    union { unsigned u; float f; } v; v.u = ((unsigned)h) << 16;
    return v.f;
}
__device__ __forceinline__ unsigned cvtpk(float lo, float hi) {
    unsigned r;
    asm("v_cvt_pk_bf16_f32 %0, %1, %2" : "=v"(r) : "v"(lo), "v"(hi));
    return r;
}

__device__ __forceinline__ void gload16(const void* gptr, void* lptr) {
    __builtin_amdgcn_global_load_lds(
        (const __attribute__((address_space(1))) unsigned int*)gptr,
        (__attribute__((address_space(3))) unsigned int*)lptr,
        16, 0, 0);
}

// ---------------------------------------------------------------- router (validated r8; packs slot in tok_list)
__global__ __launch_bounds__(256) void router_kernel(
    const float* __restrict__ x, const float* __restrict__ rw,
    const float* __restrict__ bias, unsigned short* __restrict__ x_bf,
    int* __restrict__ counts, int* __restrict__ tok_list, float* __restrict__ w_list)
{
    __shared__ float xs[HIDN];
    __shared__ double part[256];
    __shared__ double lg[NE];
    const int t = blockIdx.x, tid = threadIdx.x;

#pragma unroll
    for (int p = 0; p < 2; ++p) {
        int i = (p * 256 + tid) * 4;
        float4 v = *reinterpret_cast<const float4*>(x + (size_t)t * HIDN + i);
        *reinterpret_cast<float4*>(&xs[i]) = v;
        ushort4 b;
        b.x = f2bf(v.x); b.y = f2bf(v.y); b.z = f2bf(v.z); b.w = f2bf(v.w);
        *reinterpret_cast<ushort4*>(x_bf + (size_t)t * HIDN + i) = b;
    }
    __syncthreads();
    {
        int e = tid >> 3, l8 = tid & 7;
        const float* wrow = rw + (size_t)e * HIDN;
        double acc = 0.0;
        for (int k = l8 * 4; k < HIDN; k += 32) {
            float4 v = *reinterpret_cast<const float4*>(wrow + k);
            acc += (double)v.x * (double)xs[k]     + (double)v.y * (double)xs[k + 1]
                 + (double)v.z * (double)xs[k + 2] + (double)v.w * (double)xs[k + 3];
        }
        part[tid] = acc;
    }
    __syncthreads();
    if ((tid & 7) == 0) {
        int e = tid >> 3;
        double s = 0.0;
        for (int i = 0; i < 8; ++i) s += part[e * 8 + i];
        lg[e] = s;
    }
    __syncthreads();
    if (tid == 0) {
        const float EPS = 3e-7f;
        float s32[NE], sfc[NE], gs[NGRP];
        for (int e = 0; e < NE; ++e) {
            s32[e] = (float)(1.0 / (1.0 + exp(-lg[e])));
            sfc[e] = s32[e] + bias[e];
        }
        for (int g = 0; g < NGRP; ++g) {
            float m1 = -1e30f, m2 = -1e30f;
            for (int i = 0; i < GSZ; ++i) {
                float v = sfc[g * GSZ + i];
                if (v > m1) { m2 = m1; m1 = v; }
                else if (v > m2) m2 = v;
            }
            gs[g] = m1 + m2;
        }
        unsigned gmask = 0;
        for (int it = 0; it < TKG; ++it) {
            float best = -1e30f;
            for (int g = 0; g < NGRP; ++g)
                if (!((gmask >> g) & 1u) && gs[g] > best) best = gs[g];
            int bg = 0;
            for (int g = 0; g < NGRP; ++g)
                if (!((gmask >> g) & 1u) && gs[g] >= best - EPS) bg = g;
            gmask |= 1u << bg;
        }
        unsigned emask = 0;
        int idxs[TOPK]; float wv[TOPK];
        float wsum = 0.f;
        for (int j = 0; j < TOPK; ++j) {
            float best = -1e30f;
            for (int e = 0; e < NE; ++e)
                if (((gmask >> (e >> 2)) & 1u) && !((emask >> e) & 1u) && sfc[e] > best)
                    best = sfc[e];
            int be = 0;
            for (int e = 0; e < NE; ++e)
                if (((gmask >> (e >> 2)) & 1u) && !((emask >> e) & 1u) && sfc[e] >= best - EPS)
                    be = e;
            emask |= 1u << be;
            idxs[j] = be;
            wv[j] = s32[be];
            wsum += s32[be];
        }
        float den = wsum + 1e-20f;
        for (int j = 0; j < TOPK; ++j) {
            int e = idxs[j];
            int pos = atomicAdd(&counts[e], 1);
            tok_list[e * NTOK + pos] = t | (j << 16);
            w_list[e * NTOK + pos] = (wv[j] / den) * 2.5f;
        }
    }
}

__global__ void zero_counts_kernel(int* __restrict__ counts) {
    if (threadIdx.x < NE && blockIdx.x == 0) counts[threadIdx.x] = 0;
}

__global__ void prefix_kernel(const int* __restrict__ counts, int* __restrict__ offsets) {
    if (threadIdx.x == 0 && blockIdx.x == 0) {
        int a = 0;
        for (int e = 0; e < NE; ++e) { offsets[e] = a; a += counts[e]; }
    }
}

// ---------------------------------------------------------------- gate_up v9: v4 + half-B depth-1 prefetch, P1-first issue order
template<bool SHARED>
__global__ __launch_bounds__(256) void gateup_v9(
    const unsigned short* __restrict__ x_bf,
    const float* __restrict__ gup,
    const float* __restrict__ sgw, const float* __restrict__ suw,
    const int* __restrict__ counts, const int* __restrict__ offsets,
    const int* __restrict__ tok_list,
    unsigned short* __restrict__ h_out)
{
    const int NTT = NTOK / 128;   // 16
    int e, it, tt;
    if (SHARED) { e = 0; it = blockIdx.x / NTT; tt = blockIdx.x % NTT; }
    else {
        int logical = (blockIdx.x & 7) * 768 + (blockIdx.x >> 3);   // grid 6144 = 8*768
        e = logical / 192; int r = logical % 192; it = r / NTT; tt = r % NTT;
    }
    const int cnt = SHARED ? NTOK : counts[e];
    const int ts = tt * 128;
    if (ts >= cnt) return;
    const int base = SHARED ? 0 : offsets[e];

    __shared__ unsigned short As[128 * 64];   // 16 KB
    __shared__ unsigned short Bs[128 * 64];   // 16 KB

    const int tid = threadIdx.x;
    const int lane = tid & 63, wid = tid >> 6;
    const int wr = wid >> 1, wc = wid & 1;
    const int lr = lane & 15, lk = lane >> 4;

    const char*  aSrc[4];
    const float* bSrcF[4];
    {
        const float* Bg = SHARED ? (sgw + (size_t)it * 64 * HIDN)
                                 : (gup + (size_t)e * (2 * IM) * HIDN + (size_t)it * 64 * HIDN);
        const float* Bu = SHARED ? (suw + (size_t)it * 64 * HIDN)
                                 : (gup + (size_t)e * (2 * IM) * HIDN + (size_t)(IM + it * 64) * HIDN);
#pragma unroll
        for (int i = 0; i < 4; ++i) {
            int r = (wid * 4 + i) * 8 + (lane >> 3);
            int gslot = (lane & 7) ^ (r & 7);
            int gi = ts + r;
            int tok;
            if (SHARED) tok = (gi < NTOK) ? gi : 0;
            else        tok = (gi < cnt) ? (tok_list[e * NTOK + gi] & 0xFFFF) : 0;
            aSrc[i] = (const char*)(x_bf + (size_t)tok * HIDN) + (gslot << 4);
            const float* wrow = (r < 64) ? (Bg + (size_t)r * HIDN)
                                         : (Bu + (size_t)(r - 64) * HIDN);
            bSrcF[i] = wrow + gslot * 8;
        }
    }

    f32x4_t accg[4][2] = {};
    f32x4_t accu[4][2] = {};

    const int NK = HIDN / 64;   // 32
    float4 P0[4];   // persistent prefetched half (+16 VGPR)
#pragma unroll
    for (int i = 0; i < 4; ++i)
        P0[i] = *reinterpret_cast<const float4*>(bSrcF[i]);

    for (int t = 0; t < NK; ++t) {
        const int kByte = t * 128;
        const int kF = t * 64;
        // (1) issue P1(t) loads FIRST (oldest VMEM this iter)
        float4 p1[4];
#pragma unroll
        for (int i = 0; i < 4; ++i)
            p1[i] = *reinterpret_cast<const float4*>(bSrcF[i] + kF + 4);
        __builtin_amdgcn_sched_barrier(0);
        // (2) issue A(t) gloads (after P1, before everything else)
#pragma unroll
        for (int i = 0; i < 4; ++i)
            gload16(aSrc[i] + kByte, (char*)As + (wid * 4 + i) * 1024);
        __builtin_amdgcn_sched_barrier(0);
        // (3) cvt P0 (regs, no wait) + cvt p1 (compiler waits P1 only — oldest;
        //     A gloads stay in flight) + ds_write
#pragma unroll
        for (int i = 0; i < 4; ++i) {
            uint4 o;
            o.x = cvtpk(P0[i].x, P0[i].y);
            o.y = cvtpk(P0[i].z, P0[i].w);
            o.z = cvtpk(p1[i].x, p1[i].y);
            o.w = cvtpk(p1[i].z, p1[i].w);
            *reinterpret_cast<uint4*>((char*)Bs + (wid * 4 + i) * 1024 + lane * 16) = o;
        }
        // (4) issue P0(t+1) — newest VMEM, flies across the MFMA phase (T4)
        if (t + 1 < NK) {
            const int kFn = (t + 1) * 64;
#pragma unroll
            for (int i = 0; i < 4; ++i)
                P0[i] = *reinterpret_cast<const float4*>(bSrcF[i] + kFn);
        }
        __builtin_amdgcn_sched_barrier(0);
        // (5) drain A's 4 gloads (keep P0next's 4 in flight); last iter drain all
        if (t + 1 < NK) {
            asm volatile("s_waitcnt vmcnt(4) lgkmcnt(0)" ::: "memory");
        } else {
            asm volatile("s_waitcnt vmcnt(0) lgkmcnt(0)" ::: "memory");
        }
        __builtin_amdgcn_sched_barrier(0);
        __builtin_amdgcn_s_barrier();    // tile t fully in LDS for all waves

        const char* Ab = (const char*)As;
        const char* Bb = (const char*)Bs;
#pragma unroll
        for (int ks = 0; ks < 2; ++ks) {
            const int kb = ks * 64 + lk * 16;
            bf16x8_t a[4], bg[2], bu[2];
#pragma unroll
            for (int m = 0; m < 4; ++m) {
                int rr = wr * 64 + m * 16 + lr;
                a[m] = *reinterpret_cast<const bf16x8_t*>(Ab + rr * 128 + (kb ^ ((rr & 7) << 4)));
            }
#pragma unroll
            for (int n = 0; n < 2; ++n) {
                int rg = wc * 32 + n * 16 + lr;
                int ru = 64 + wc * 32 + n * 16 + lr;
                bg[n] = *reinterpret_cast<const bf16x8_t*>(Bb + rg * 128 + (kb ^ ((rg & 7) << 4)));
                bu[n] = *reinterpret_cast<const bf16x8_t*>(Bb + ru * 128 + (kb ^ ((ru & 7) << 4)));
            }
#pragma unroll
            for (int m = 0; m < 4; ++m)
#pragma unroll
                for (int n = 0; n < 2; ++n) {
                    accg[m][n] = __builtin_amdgcn_mfma_f32_16x16x32_bf16(a[m], bg[n], accg[m][n], 0, 0, 0);
                    accu[m][n] = __builtin_amdgcn_mfma_f32_16x16x32_bf16(a[m], bu[n], accu[m][n], 0, 0, 0);
                }
        }
        __builtin_amdgcn_s_barrier();    // all waves done reading As/Bs
    }

#pragma unroll
    for (int m = 0; m < 4; ++m)
#pragma unroll
        for (int n = 0; n < 2; ++n)
#pragma unroll
            for (int j = 0; j < 4; ++j) {
                int r = wr * 64 + m * 16 + lk * 4 + j;
                int gi = ts + r;
                if (gi < cnt) {
                    int ci = it * 64 + wc * 32 + n * 16 + lr;
                    float g = accg[m][n][j], u = accu[m][n][j];
                    float h = g / (1.f + expf(-g)) * u;   // silu(g)*u
                    h_out[(size_t)(base + gi) * IM + ci] = f2bf(h);
                }
            }
}

// ---------------------------------------------------------------- down v8 (R19/R20/R21 validated) — bf16 slot stores
template<bool SHARED>
__global__ __launch_bounds__(256) void down_v8(
    const unsigned short* __restrict__ h_in,
    const float* __restrict__ dnp, const float* __restrict__ sdw,
    const int* __restrict__ counts, const int* __restrict__ offsets,
    const int* __restrict__ tok_list, const float* __restrict__ w_list,
    unsigned short* __restrict__ y_slot, float* __restrict__ out)
{
    const int NTT = NTOK / 128;   // 16
    int e, ct, tt;
    if (SHARED) { e = 0; ct = blockIdx.x / NTT; tt = blockIdx.x % NTT; }
    else {
        int logical = (blockIdx.x & 7) * 1024 + (blockIdx.x >> 3);   // grid 8192 = 8*1024
        e = logical / 256; int r = logical % 256; ct = r / NTT; tt = r % NTT;
    }
    const int cnt = SHARED ? NTOK : counts[e];
    const int ts = tt * 128;
    if (ts >= cnt) return;
    const int base = SHARED ? 0 : offsets[e];

    __shared__ unsigned short As[128 * 64];
    __shared__ unsigned short Bs[128 * 64];

    const int tid = threadIdx.x;
    const int lane = tid & 63, wid = tid >> 6;
    const int wr = wid >> 1, wc = wid & 1;
    const int lr = lane & 15, lk = lane >> 4;

    const int TOTROW = SHARED ? NTOK : (NTOK * TOPK);
    const char*  aSrc[4];
    const float* bSrcF[4];
    {
        const float* Bw = SHARED ? (sdw + (size_t)ct * 128 * IM)
                                 : (dnp + (size_t)e * HIDN * IM + (size_t)ct * 128 * IM);
#pragma unroll
        for (int i = 0; i < 4; ++i) {
            int r = (wid * 4 + i) * 8 + (lane >> 3);
            int gslot = (lane & 7) ^ (r & 7);
            int gi = base + ts + r;
            if (gi > TOTROW - 1) gi = TOTROW - 1;
            aSrc[i] = (const char*)(h_in + (size_t)gi * IM) + (gslot << 4);
            bSrcF[i] = Bw + (size_t)r * IM + gslot * 8;
        }
    }

    f32x4_t acc[4][4] = {};

    const int NK = IM / 64;   // 12
    float4 P0[4], P1[4];
#pragma unroll
    for (int i = 0; i < 4; ++i) {
        P0[i] = *reinterpret_cast<const float4*>(bSrcF[i]);
        P1[i] = *reinterpret_cast<const float4*>(bSrcF[i] + 4);
    }

    for (int t = 0; t < NK; ++t) {
        const int kByte = t * 128;
        // (1) issue A(t) gloads FIRST (oldest VMEM this iter)
#pragma unroll
        for (int i = 0; i < 4; ++i)
            gload16(aSrc[i] + kByte, (char*)As + (wid * 4 + i) * 1024);
        __builtin_amdgcn_sched_barrier(0);
        // (2) cvt B(t) + ds_write
#pragma unroll
        for (int i = 0; i < 4; ++i) {
            uint4 o;
            o.x = cvtpk(P0[i].x, P0[i].y);
            o.y = cvtpk(P0[i].z, P0[i].w);
            o.z = cvtpk(P1[i].x, P1[i].y);
            o.w = cvtpk(P1[i].z, P1[i].w);
            *reinterpret_cast<uint4*>((char*)Bs + (wid * 4 + i) * 1024 + lane * 16) = o;
        }
        // (3) issue B(t+1) — newest VMEM, flies across MFMA (T4)
        if (t + 1 < NK) {
            const int kF = (t + 1) * 64;
#pragma unroll
            for (int i = 0; i < 4; ++i) {
                P0[i] = *reinterpret_cast<const float4*>(bSrcF[i] + kF);
                P1[i] = *reinterpret_cast<const float4*>(bSrcF[i] + kF + 4);
            }
        }
        __builtin_amdgcn_sched_barrier(0);
        // (4) drain exactly the 4 A(t) gloads (+ ds_writes); keep B(t+1)'s 8 in flight
        if (t + 1 < NK) {
            asm volatile("s_waitcnt vmcnt(8) lgkmcnt(0)" ::: "memory");
        } else {
            asm volatile("s_waitcnt vmcnt(0) lgkmcnt(0)" ::: "memory");
        }
        __builtin_amdgcn_sched_barrier(0);
        __builtin_amdgcn_s_barrier();

        const char* Ab = (const char*)As;
        const char* Bb = (const char*)Bs;
#pragma unroll
        for (int ks = 0; ks < 2; ++ks) {
            const int kb = ks * 64 + lk * 16;
            bf16x8_t a[4], b[4];
#pragma unroll
            for (int m = 0; m < 4; ++m) {
                int rr = wr * 64 + m * 16 + lr;
                a[m] = *reinterpret_cast<const bf16x8_t*>(Ab + rr * 128 + (kb ^ ((rr & 7) << 4)));
            }
#pragma unroll
            for (int n = 0; n < 4; ++n) {
                int rc = wc * 64 + n * 16 + lr;
                b[n] = *reinterpret_cast<const bf16x8_t*>(Bb + rc * 128 + (kb ^ ((rc & 7) << 4)));
            }
#pragma unroll
            for (int m = 0; m < 4; ++m)
#pragma unroll
                for (int n = 0; n < 4; ++n)
                    acc[m][n] = __builtin_amdgcn_mfma_f32_16x16x32_bf16(a[m], b[n], acc[m][n], 0, 0, 0);
        }
        __builtin_amdgcn_s_barrier();
    }

#pragma unroll
    for (int m = 0; m < 4; ++m)
#pragma unroll
        for (int j = 0; j < 4; ++j) {
            int r = wr * 64 + m * 16 + lk * 4 + j;
            int gi = ts + r;
            if (gi < cnt) {
                if (SHARED) {
#pragma unroll
                    for (int n = 0; n < 4; ++n)
                        out[(size_t)gi * HIDN + ct * 128 + wc * 64 + n * 16 + lr] = acc[m][n][j];
                } else {
                    int pk = tok_list[e * NTOK + gi];
                    int tkn = pk & 0xFFFF, sl = pk >> 16;
                    float wv = w_list[e * NTOK + gi];
                    unsigned short* dst = y_slot + ((size_t)tkn * TOPK + sl) * HIDN + ct * 128 + wc * 64 + lr;
#pragma unroll
                    for (int n = 0; n < 4; ++n)
                        dst[n * 16] = f2bf(wv * acc[m][n][j]);
                }
            }
        }
}

// ---------------------------------------------------------------- slot reduce: out += sum of 8 bf16 slots
__global__ __launch_bounds__(256) void reduce_kernel(
    const unsigned short* __restrict__ y_slot, float* __restrict__ out)
{
    size_t p = (size_t)blockIdx.x * 256 + threadIdx.x;   // < NTOK*HIDN/4
    int t = (int)(p / (HIDN / 4));
    int c = (int)(p % (HIDN / 4)) * 4;
    float4 s = *reinterpret_cast<const float4*>(out + (size_t)t * HIDN + c);
#pragma unroll
    for (int sl = 0; sl < TOPK; ++sl) {
        uint2 v = *reinterpret_cast<const uint2*>(y_slot + ((size_t)t * TOPK + sl) * HIDN + c);
        s.x += bf2f((unsigned short)(v.x & 0xFFFF));
        s.y += bf2f((unsigned short)(v.x >> 16));
        s.z += bf2f((unsigned short)(v.y & 0xFFFF));
        s.w += bf2f((unsigned short)(v.y >> 16));
    }
    *reinterpret_cast<float4*>(out + (size_t)t * HIDN + c) = s;
}

// ---------------------------------------------------------------- launch
extern "C" void kernel_launch(void* const* d_in, const int* in_sizes, int n_in,
                              void* d_out, int out_size, void* d_ws, size_t ws_size,
                              hipStream_t stream)
{
    (void)in_sizes; (void)n_in; (void)out_size; (void)ws_size;
    const float* x    = (const float*)d_in[0];
    const float* rw   = (const float*)d_in[1];
    const float* bias = (const float*)d_in[2];
    const float* gup  = (const float*)d_in[3];
    const float* dnp  = (const float*)d_in[4];
    const float* sgw  = (const float*)d_in[5];
    const float* suw  = (const float*)d_in[6];
    const float* sdw  = (const float*)d_in[7];
    float* out = (float*)d_out;

    char* w = (char*)d_ws;
    unsigned short* x_bf   = (unsigned short*)w; w += (size_t)NTOK * HIDN * 2;
    unsigned short* h_buf  = (unsigned short*)w; w += (size_t)NTOK * TOPK * IM * 2;
    unsigned short* h_sh   = (unsigned short*)w; w += (size_t)NTOK * IM * 2;
    int*   tok_list = (int*)w;   w += (size_t)NE * NTOK * 4;
    float* w_list   = (float*)w; w += (size_t)NE * NTOK * 4;
    int*   counts   = (int*)w;   w += 128;
    int*   offsets  = (int*)w;   w += 128;
    unsigned short* y_slot = (unsigned short*)w; w += (size_t)NTOK * TOPK * HIDN * 2;  // 67 MB

    zero_counts_kernel<<<1, 64, 0, stream>>>(counts);
    router_kernel<<<NTOK, 256, 0, stream>>>(x, rw, bias, x_bf, counts, tok_list, w_list);
    prefix_kernel<<<1, 64, 0, stream>>>(counts, offsets);

    gateup_v9<false><<<NE * (IM / 64) * (NTOK / 128), 256, 0, stream>>>(
        x_bf, gup, sgw, suw, counts, offsets, tok_list, h_buf);
    gateup_v9<true><<<(IM / 64) * (NTOK / 128), 256, 0, stream>>>(
        x_bf, gup, sgw, suw, counts, offsets, tok_list, h_sh);
    // shared down writes `out` (assignment) first; routed down writes bf16 slots; reduce sums.
    down_v8<true><<<(HIDN / 128) * (NTOK / 128), 256, 0, stream>>>(
        h_sh, dnp, sdw, counts, offsets, tok_list, w_list, y_slot, out);
    down_v8<false><<<NE * (HIDN / 128) * (NTOK / 128), 256, 0, stream>>>(
        h_buf, dnp, sdw, counts, offsets, tok_list, w_list, y_slot, out);
    reduce_kernel<<<NTOK * HIDN / 4 / 256, 256, 0, stream>>>(y_slot, out);
}

// Round 23
// 637.287 us; speedup vs baseline: 1.0388x; 1.0388x over previous
//
#include <hip/hip_runtime.h>
#include <cstdint>
#include <cstddef>

#define NTOK  2048
#define HIDN  2048
#define IM    768
#define NE    32
#define TOPK  8
#define NGRP  8
#define GSZ   4
#define TKG   4

typedef __attribute__((ext_vector_type(8))) short bf16x8_t;
typedef __attribute__((ext_vector_type(4))) float f32x4_t;

__device__ __forceinline__ unsigned short f2bf(float f) {
    union { float f; unsigned u; } v; v.f = f;
    unsigned r = v.u + 0x7FFFu + ((v.u >> 16) & 1u);
    return (unsigned short)(r >> 16);
}
__device__ __forceinline__ float bf2f(unsigned short h) {
    union { unsigned u; float f; } v; v.u = ((unsigned)h) << 16;
    return v.f;
}
__device__ __forceinline__ unsigned cvtpk(float lo, float hi) {
    unsigned r;
    asm("v_cvt_pk_bf16_f32 %0, %1, %2" : "=v"(r) : "v"(lo), "v"(hi));
    return r;
}

__device__ __forceinline__ void gload16(const void* gptr, void* lptr) {
    __builtin_amdgcn_global_load_lds(
        (const __attribute__((address_space(1))) unsigned int*)gptr,
        (__attribute__((address_space(3))) unsigned int*)lptr,
        16, 0, 0);
}

// ---------------------------------------------------------------- router (validated r8; packs slot in tok_list)
__global__ __launch_bounds__(256) void router_kernel(
    const float* __restrict__ x, const float* __restrict__ rw,
    const float* __restrict__ bias, unsigned short* __restrict__ x_bf,
    int* __restrict__ counts, int* __restrict__ tok_list, float* __restrict__ w_list)
{
    __shared__ float xs[HIDN];
    __shared__ double part[256];
    __shared__ double lg[NE];
    const int t = blockIdx.x, tid = threadIdx.x;

#pragma unroll
    for (int p = 0; p < 2; ++p) {
        int i = (p * 256 + tid) * 4;
        float4 v = *reinterpret_cast<const float4*>(x + (size_t)t * HIDN + i);
        *reinterpret_cast<float4*>(&xs[i]) = v;
        ushort4 b;
        b.x = f2bf(v.x); b.y = f2bf(v.y); b.z = f2bf(v.z); b.w = f2bf(v.w);
        *reinterpret_cast<ushort4*>(x_bf + (size_t)t * HIDN + i) = b;
    }
    __syncthreads();
    {
        int e = tid >> 3, l8 = tid & 7;
        const float* wrow = rw + (size_t)e * HIDN;
        double acc = 0.0;
        for (int k = l8 * 4; k < HIDN; k += 32) {
            float4 v = *reinterpret_cast<const float4*>(wrow + k);
            acc += (double)v.x * (double)xs[k]     + (double)v.y * (double)xs[k + 1]
                 + (double)v.z * (double)xs[k + 2] + (double)v.w * (double)xs[k + 3];
        }
        part[tid] = acc;
    }
    __syncthreads();
    if ((tid & 7) == 0) {
        int e = tid >> 3;
        double s = 0.0;
        for (int i = 0; i < 8; ++i) s += part[e * 8 + i];
        lg[e] = s;
    }
    __syncthreads();
    if (tid == 0) {
        const float EPS = 3e-7f;
        float s32[NE], sfc[NE], gs[NGRP];
        for (int e = 0; e < NE; ++e) {
            s32[e] = (float)(1.0 / (1.0 + exp(-lg[e])));
            sfc[e] = s32[e] + bias[e];
        }
        for (int g = 0; g < NGRP; ++g) {
            float m1 = -1e30f, m2 = -1e30f;
            for (int i = 0; i < GSZ; ++i) {
                float v = sfc[g * GSZ + i];
                if (v > m1) { m2 = m1; m1 = v; }
                else if (v > m2) m2 = v;
            }
            gs[g] = m1 + m2;
        }
        unsigned gmask = 0;
        for (int it = 0; it < TKG; ++it) {
            float best = -1e30f;
            for (int g = 0; g < NGRP; ++g)
                if (!((gmask >> g) & 1u) && gs[g] > best) best = gs[g];
            int bg = 0;
            for (int g = 0; g < NGRP; ++g)
                if (!((gmask >> g) & 1u) && gs[g] >= best - EPS) bg = g;
            gmask |= 1u << bg;
        }
        unsigned emask = 0;
        int idxs[TOPK]; float wv[TOPK];
        float wsum = 0.f;
        for (int j = 0; j < TOPK; ++j) {
            float best = -1e30f;
            for (int e = 0; e < NE; ++e)
                if (((gmask >> (e >> 2)) & 1u) && !((emask >> e) & 1u) && sfc[e] > best)
                    best = sfc[e];
            int be = 0;
            for (int e = 0; e < NE; ++e)
                if (((gmask >> (e >> 2)) & 1u) && !((emask >> e) & 1u) && sfc[e] >= best - EPS)
                    be = e;
            emask |= 1u << be;
            idxs[j] = be;
            wv[j] = s32[be];
            wsum += s32[be];
        }
        float den = wsum + 1e-20f;
        for (int j = 0; j < TOPK; ++j) {
            int e = idxs[j];
            int pos = atomicAdd(&counts[e], 1);
            tok_list[e * NTOK + pos] = t | (j << 16);
            w_list[e * NTOK + pos] = (wv[j] / den) * 2.5f;
        }
    }
}

__global__ void zero_counts_kernel(int* __restrict__ counts) {
    if (threadIdx.x < NE && blockIdx.x == 0) counts[threadIdx.x] = 0;
}

__global__ void prefix_kernel(const int* __restrict__ counts, int* __restrict__ offsets) {
    if (threadIdx.x == 0 && blockIdx.x == 0) {
        int a = 0;
        for (int e = 0; e < NE; ++e) { offsets[e] = a; a += counts[e]; }
    }
}

// ---------------------------------------------------------------- gate_up v4 (R14/R17/R20/R21 validated)
template<bool SHARED>
__global__ __launch_bounds__(256) void gateup_v4(
    const unsigned short* __restrict__ x_bf,
    const float* __restrict__ gup,
    const float* __restrict__ sgw, const float* __restrict__ suw,
    const int* __restrict__ counts, const int* __restrict__ offsets,
    const int* __restrict__ tok_list,
    unsigned short* __restrict__ h_out)
{
    const int NTT = NTOK / 128;   // 16
    int e, it, tt;
    if (SHARED) { e = 0; it = blockIdx.x / NTT; tt = blockIdx.x % NTT; }
    else {
        int logical = (blockIdx.x & 7) * 768 + (blockIdx.x >> 3);   // grid 6144 = 8*768
        e = logical / 192; int r = logical % 192; it = r / NTT; tt = r % NTT;
    }
    const int cnt = SHARED ? NTOK : counts[e];
    const int ts = tt * 128;
    if (ts >= cnt) return;
    const int base = SHARED ? 0 : offsets[e];

    __shared__ unsigned short As[128 * 64];   // 16 KB
    __shared__ unsigned short Bs[128 * 64];   // 16 KB

    const int tid = threadIdx.x;
    const int lane = tid & 63, wid = tid >> 6;
    const int wr = wid >> 1, wc = wid & 1;
    const int lr = lane & 15, lk = lane >> 4;

    const char*  aSrc[4];
    const float* bSrcF[4];
    {
        const float* Bg = SHARED ? (sgw + (size_t)it * 64 * HIDN)
                                 : (gup + (size_t)e * (2 * IM) * HIDN + (size_t)it * 64 * HIDN);
        const float* Bu = SHARED ? (suw + (size_t)it * 64 * HIDN)
                                 : (gup + (size_t)e * (2 * IM) * HIDN + (size_t)(IM + it * 64) * HIDN);
#pragma unroll
        for (int i = 0; i < 4; ++i) {
            int r = (wid * 4 + i) * 8 + (lane >> 3);
            int gslot = (lane & 7) ^ (r & 7);
            int gi = ts + r;
            int tok;
            if (SHARED) tok = (gi < NTOK) ? gi : 0;
            else        tok = (gi < cnt) ? (tok_list[e * NTOK + gi] & 0xFFFF) : 0;
            aSrc[i] = (const char*)(x_bf + (size_t)tok * HIDN) + (gslot << 4);
            const float* wrow = (r < 64) ? (Bg + (size_t)r * HIDN)
                                         : (Bu + (size_t)(r - 64) * HIDN);
            bSrcF[i] = wrow + gslot * 8;
        }
    }

    f32x4_t accg[4][2] = {};
    f32x4_t accu[4][2] = {};

    const int NK = HIDN / 64;   // 32
    for (int t = 0; t < NK; ++t) {
        if (t) __syncthreads();
        const int kByte = t * 128;
        const int kF = t * 64;
#pragma unroll
        for (int i = 0; i < 4; ++i)
            gload16(aSrc[i] + kByte, (char*)As + (wid * 4 + i) * 1024);
        float4 b0[4], b1[4];
#pragma unroll
        for (int i = 0; i < 4; ++i) {
            b0[i] = *reinterpret_cast<const float4*>(bSrcF[i] + kF);
            b1[i] = *reinterpret_cast<const float4*>(bSrcF[i] + kF + 4);
        }
#pragma unroll
        for (int i = 0; i < 4; ++i) {
            uint4 o;
            o.x = cvtpk(b0[i].x, b0[i].y);
            o.y = cvtpk(b0[i].z, b0[i].w);
            o.z = cvtpk(b1[i].x, b1[i].y);
            o.w = cvtpk(b1[i].z, b1[i].w);
            *reinterpret_cast<uint4*>((char*)Bs + (wid * 4 + i) * 1024 + lane * 16) = o;
        }
        __syncthreads();

        const char* Ab = (const char*)As;
        const char* Bb = (const char*)Bs;
#pragma unroll
        for (int ks = 0; ks < 2; ++ks) {
            const int kb = ks * 64 + lk * 16;
            bf16x8_t a[4], bg[2], bu[2];
#pragma unroll
            for (int m = 0; m < 4; ++m) {
                int rr = wr * 64 + m * 16 + lr;
                a[m] = *reinterpret_cast<const bf16x8_t*>(Ab + rr * 128 + (kb ^ ((rr & 7) << 4)));
            }
#pragma unroll
            for (int n = 0; n < 2; ++n) {
                int rg = wc * 32 + n * 16 + lr;
                int ru = 64 + wc * 32 + n * 16 + lr;
                bg[n] = *reinterpret_cast<const bf16x8_t*>(Bb + rg * 128 + (kb ^ ((rg & 7) << 4)));
                bu[n] = *reinterpret_cast<const bf16x8_t*>(Bb + ru * 128 + (kb ^ ((ru & 7) << 4)));
            }
#pragma unroll
            for (int m = 0; m < 4; ++m)
#pragma unroll
                for (int n = 0; n < 2; ++n) {
                    accg[m][n] = __builtin_amdgcn_mfma_f32_16x16x32_bf16(a[m], bg[n], accg[m][n], 0, 0, 0);
                    accu[m][n] = __builtin_amdgcn_mfma_f32_16x16x32_bf16(a[m], bu[n], accu[m][n], 0, 0, 0);
                }
        }
    }

#pragma unroll
    for (int m = 0; m < 4; ++m)
#pragma unroll
        for (int n = 0; n < 2; ++n)
#pragma unroll
            for (int j = 0; j < 4; ++j) {
                int r = wr * 64 + m * 16 + lk * 4 + j;
                int gi = ts + r;
                if (gi < cnt) {
                    int ci = it * 64 + wc * 32 + n * 16 + lr;
                    float g = accg[m][n][j], u = accu[m][n][j];
                    float h = g / (1.f + expf(-g)) * u;   // silu(g)*u
                    h_out[(size_t)(base + gi) * IM + ci] = f2bf(h);
                }
            }
}

// ---------------------------------------------------------------- down v8 (R19/R20/R21 validated) — bf16 slot stores
template<bool SHARED>
__global__ __launch_bounds__(256) void down_v8(
    const unsigned short* __restrict__ h_in,
    const float* __restrict__ dnp, const float* __restrict__ sdw,
    const int* __restrict__ counts, const int* __restrict__ offsets,
    const int* __restrict__ tok_list, const float* __restrict__ w_list,
    unsigned short* __restrict__ y_slot, float* __restrict__ out)
{
    const int NTT = NTOK / 128;   // 16
    int e, ct, tt;
    if (SHARED) { e = 0; ct = blockIdx.x / NTT; tt = blockIdx.x % NTT; }
    else {
        int logical = (blockIdx.x & 7) * 1024 + (blockIdx.x >> 3);   // grid 8192 = 8*1024
        e = logical / 256; int r = logical % 256; ct = r / NTT; tt = r % NTT;
    }
    const int cnt = SHARED ? NTOK : counts[e];
    const int ts = tt * 128;
    if (ts >= cnt) return;
    const int base = SHARED ? 0 : offsets[e];

    __shared__ unsigned short As[128 * 64];
    __shared__ unsigned short Bs[128 * 64];

    const int tid = threadIdx.x;
    const int lane = tid & 63, wid = tid >> 6;
    const int wr = wid >> 1, wc = wid & 1;
    const int lr = lane & 15, lk = lane >> 4;

    const int TOTROW = SHARED ? NTOK : (NTOK * TOPK);
    const char*  aSrc[4];
    const float* bSrcF[4];
    {
        const float* Bw = SHARED ? (sdw + (size_t)ct * 128 * IM)
                                 : (dnp + (size_t)e * HIDN * IM + (size_t)ct * 128 * IM);
#pragma unroll
        for (int i = 0; i < 4; ++i) {
            int r = (wid * 4 + i) * 8 + (lane >> 3);
            int gslot = (lane & 7) ^ (r & 7);
            int gi = base + ts + r;
            if (gi > TOTROW - 1) gi = TOTROW - 1;
            aSrc[i] = (const char*)(h_in + (size_t)gi * IM) + (gslot << 4);
            bSrcF[i] = Bw + (size_t)r * IM + gslot * 8;
        }
    }

    f32x4_t acc[4][4] = {};

    const int NK = IM / 64;   // 12
    float4 P0[4], P1[4];
#pragma unroll
    for (int i = 0; i < 4; ++i) {
        P0[i] = *reinterpret_cast<const float4*>(bSrcF[i]);
        P1[i] = *reinterpret_cast<const float4*>(bSrcF[i] + 4);
    }

    for (int t = 0; t < NK; ++t) {
        const int kByte = t * 128;
        // (1) issue A(t) gloads FIRST (oldest VMEM this iter)
#pragma unroll
        for (int i = 0; i < 4; ++i)
            gload16(aSrc[i] + kByte, (char*)As + (wid * 4 + i) * 1024);
        __builtin_amdgcn_sched_barrier(0);
        // (2) cvt B(t) + ds_write
#pragma unroll
        for (int i = 0; i < 4; ++i) {
            uint4 o;
            o.x = cvtpk(P0[i].x, P0[i].y);
            o.y = cvtpk(P0[i].z, P0[i].w);
            o.z = cvtpk(P1[i].x, P1[i].y);
            o.w = cvtpk(P1[i].z, P1[i].w);
            *reinterpret_cast<uint4*>((char*)Bs + (wid * 4 + i) * 1024 + lane * 16) = o;
        }
        // (3) issue B(t+1) — newest VMEM, flies across MFMA (T4)
        if (t + 1 < NK) {
            const int kF = (t + 1) * 64;
#pragma unroll
            for (int i = 0; i < 4; ++i) {
                P0[i] = *reinterpret_cast<const float4*>(bSrcF[i] + kF);
                P1[i] = *reinterpret_cast<const float4*>(bSrcF[i] + kF + 4);
            }
        }
        __builtin_amdgcn_sched_barrier(0);
        // (4) drain exactly the 4 A(t) gloads (+ ds_writes); keep B(t+1)'s 8 in flight
        if (t + 1 < NK) {
            asm volatile("s_waitcnt vmcnt(8) lgkmcnt(0)" ::: "memory");
        } else {
            asm volatile("s_waitcnt vmcnt(0) lgkmcnt(0)" ::: "memory");
        }
        __builtin_amdgcn_sched_barrier(0);
        __builtin_amdgcn_s_barrier();

        const char* Ab = (const char*)As;
        const char* Bb = (const char*)Bs;
#pragma unroll
        for (int ks = 0; ks < 2; ++ks) {
            const int kb = ks * 64 + lk * 16;
            bf16x8_t a[4], b[4];
#pragma unroll
            for (int m = 0; m < 4; ++m) {
                int rr = wr * 64 + m * 16 + lr;
                a[m] = *reinterpret_cast<const bf16x8_t*>(Ab + rr * 128 + (kb ^ ((rr & 7) << 4)));
            }
#pragma unroll
            for (int n = 0; n < 4; ++n) {
                int rc = wc * 64 + n * 16 + lr;
                b[n] = *reinterpret_cast<const bf16x8_t*>(Bb + rc * 128 + (kb ^ ((rc & 7) << 4)));
            }
#pragma unroll
            for (int m = 0; m < 4; ++m)
#pragma unroll
                for (int n = 0; n < 4; ++n)
                    acc[m][n] = __builtin_amdgcn_mfma_f32_16x16x32_bf16(a[m], b[n], acc[m][n], 0, 0, 0);
        }
        __builtin_amdgcn_s_barrier();
    }

#pragma unroll
    for (int m = 0; m < 4; ++m)
#pragma unroll
        for (int j = 0; j < 4; ++j) {
            int r = wr * 64 + m * 16 + lk * 4 + j;
            int gi = ts + r;
            if (gi < cnt) {
                if (SHARED) {
#pragma unroll
                    for (int n = 0; n < 4; ++n)
                        out[(size_t)gi * HIDN + ct * 128 + wc * 64 + n * 16 + lr] = acc[m][n][j];
                } else {
                    int pk = tok_list[e * NTOK + gi];
                    int tkn = pk & 0xFFFF, sl = pk >> 16;
                    float wv = w_list[e * NTOK + gi];
                    unsigned short* dst = y_slot + ((size_t)tkn * TOPK + sl) * HIDN + ct * 128 + wc * 64 + lr;
#pragma unroll
                    for (int n = 0; n < 4; ++n)
                        dst[n * 16] = f2bf(wv * acc[m][n][j]);
                }
            }
        }
}

// ---------------------------------------------------------------- slot reduce: out += sum of 8 bf16 slots
__global__ __launch_bounds__(256) void reduce_kernel(
    const unsigned short* __restrict__ y_slot, float* __restrict__ out)
{
    size_t p = (size_t)blockIdx.x * 256 + threadIdx.x;   // < NTOK*HIDN/4
    int t = (int)(p / (HIDN / 4));
    int c = (int)(p % (HIDN / 4)) * 4;
    float4 s = *reinterpret_cast<const float4*>(out + (size_t)t * HIDN + c);
#pragma unroll
    for (int sl = 0; sl < TOPK; ++sl) {
        uint2 v = *reinterpret_cast<const uint2*>(y_slot + ((size_t)t * TOPK + sl) * HIDN + c);
        s.x += bf2f((unsigned short)(v.x & 0xFFFF));
        s.y += bf2f((unsigned short)(v.x >> 16));
        s.z += bf2f((unsigned short)(v.y & 0xFFFF));
        s.w += bf2f((unsigned short)(v.y >> 16));
    }
    *reinterpret_cast<float4*>(out + (size_t)t * HIDN + c) = s;
}

// ---------------------------------------------------------------- launch
extern "C" void kernel_launch(void* const* d_in, const int* in_sizes, int n_in,
                              void* d_out, int out_size, void* d_ws, size_t ws_size,
                              hipStream_t stream)
{
    (void)in_sizes; (void)n_in; (void)out_size; (void)ws_size;
    const float* x    = (const float*)d_in[0];
    const float* rw   = (const float*)d_in[1];
    const float* bias = (const float*)d_in[2];
    const float* gup  = (const float*)d_in[3];
    const float* dnp  = (const float*)d_in[4];
    const float* sgw  = (const float*)d_in[5];
    const float* suw  = (const float*)d_in[6];
    const float* sdw  = (const float*)d_in[7];
    float* out = (float*)d_out;

    char* w = (char*)d_ws;
    unsigned short* x_bf   = (unsigned short*)w; w += (size_t)NTOK * HIDN * 2;
    unsigned short* h_buf  = (unsigned short*)w; w += (size_t)NTOK * TOPK * IM * 2;
    unsigned short* h_sh   = (unsigned short*)w; w += (size_t)NTOK * IM * 2;
    int*   tok_list = (int*)w;   w += (size_t)NE * NTOK * 4;
    float* w_list   = (float*)w; w += (size_t)NE * NTOK * 4;
    int*   counts   = (int*)w;   w += 128;
    int*   offsets  = (int*)w;   w += 128;
    unsigned short* y_slot = (unsigned short*)w; w += (size_t)NTOK * TOPK * HIDN * 2;  // 67 MB

    zero_counts_kernel<<<1, 64, 0, stream>>>(counts);
    router_kernel<<<NTOK, 256, 0, stream>>>(x, rw, bias, x_bf, counts, tok_list, w_list);
    prefix_kernel<<<1, 64, 0, stream>>>(counts, offsets);

    gateup_v4<false><<<NE * (IM / 64) * (NTOK / 128), 256, 0, stream>>>(
        x_bf, gup, sgw, suw, counts, offsets, tok_list, h_buf);
    gateup_v4<true><<<(IM / 64) * (NTOK / 128), 256, 0, stream>>>(
        x_bf, gup, sgw, suw, counts, offsets, tok_list, h_sh);
    // shared down writes `out` (assignment) first; routed down writes bf16 slots; reduce sums.
    down_v8<true><<<(HIDN / 128) * (NTOK / 128), 256, 0, stream>>>(
        h_sh, dnp, sdw, counts, offsets, tok_list, w_list, y_slot, out);
    down_v8<false><<<NE * (HIDN / 128) * (NTOK / 128), 256, 0, stream>>>(
        h_buf, dnp, sdw, counts, offsets, tok_list, w_list, y_slot, out);
    reduce_kernel<<<NTOK * HIDN / 4 / 256, 256, 0, stream>>>(y_slot, out);
}